// Round 1
// baseline (352.259 us; speedup 1.0000x reference)
//
#include <hip/hip_runtime.h>

// YOLOv1 loss on MI355X — single-pass memory-bound reduction.
// N=4096, S=14, B=2, C=20. 802,816 cells, ~192 MB input, 5 scalar outputs.

constexpr int NCELL = 4096 * 14 * 14;   // 802816
constexpr float INV_BS = 1.0f / 4096.0f;
constexpr float L_COORD = 5.0f;
constexpr float L_NOOBJ = 0.5f;

// IoU of the "corner-ized" boxes, arithmetic matched to the reference:
// corners = xy -+ 0.5*wh^2 ; areas from corner differences (not 2*half).
__device__ __forceinline__ float iou_corners(float4 t, float4 p) {
    float thx = 0.5f * t.z * t.z;
    float thy = 0.5f * t.w * t.w;
    float t_l = t.x - thx, t_t = t.y - thy;
    float t_r = t.x + thx, t_b = t.y + thy;
    float phx = 0.5f * p.z * p.z;
    float phy = 0.5f * p.w * p.w;
    float p_l = p.x - phx, p_t = p.y - phy;
    float p_r = p.x + phx, p_b = p.y + phy;
    float ltx = fmaxf(t_l, p_l), lty = fmaxf(t_t, p_t);
    float rbx = fminf(t_r, p_r), rby = fminf(t_b, p_b);
    float wx = fmaxf(rbx - ltx, 0.0f), wy = fmaxf(rby - lty, 0.0f);
    float inter = wx * wy;
    float a1 = (t_r - t_l) * (t_b - t_t);
    float a2 = (p_r - p_l) * (p_b - p_t);
    return inter / (a1 + a2 - inter);
}

__global__ __launch_bounds__(256) void yolo_loss_kernel(
    const float* __restrict__ pred_cls,    // [NCELL][20]
    const float* __restrict__ pred_resp,   // [NCELL][2]
    const float* __restrict__ pred_bb,     // [NCELL][8]
    const float* __restrict__ label_cls,   // [NCELL][20]
    const float* __restrict__ label_resp,  // [NCELL][2]
    const float* __restrict__ label_bb,    // [NCELL][8]
    float* __restrict__ out)               // [5]
{
    int cell = blockIdx.x * 256 + threadIdx.x;

    float coord = 0.0f, cls = 0.0f, pobj = 0.0f, nobj = 0.0f, iouL = 0.0f;

    if (cell < NCELL) {
        // response (always needed): 8 + 8 bytes per cell
        float2 lr = *reinterpret_cast<const float2*>(label_resp + (size_t)cell * 2);
        float2 pr = *reinterpret_cast<const float2*>(pred_resp  + (size_t)cell * 2);
        bool obj = lr.x > 0.0f;   // label_response is {0,1}; noobj = !obj

        if (!obj) {
            float d0 = pr.x - lr.x, d1 = pr.y - lr.y;
            nobj = d0 * d0 + d1 * d1;
        } else {
            // ---- classification loss (20 floats x 2 arrays, float4-vectorized) ----
            const float4* pc = reinterpret_cast<const float4*>(pred_cls  + (size_t)cell * 20);
            const float4* lc = reinterpret_cast<const float4*>(label_cls + (size_t)cell * 20);
            #pragma unroll
            for (int k = 0; k < 5; ++k) {
                float4 a = pc[k], b = lc[k];
                float dx = a.x - b.x, dy = a.y - b.y, dz = a.z - b.z, dw = a.w - b.w;
                cls += dx * dx + dy * dy + dz * dz + dw * dw;
            }

            // ---- bboxes: 2 boxes x 4 params each side ----
            const float4* pbp = reinterpret_cast<const float4*>(pred_bb  + (size_t)cell * 8);
            const float4* tbp = reinterpret_cast<const float4*>(label_bb + (size_t)cell * 8);
            float4 pb0 = pbp[0], pb1 = pbp[1];
            float4 tb0 = tbp[0], tb1 = tbp[1];

            float iou0 = iou_corners(tb0, pb0);
            float iou1 = iou_corners(tb1, pb1);

            // jnp.argmax returns FIRST max -> best=1 only on strict greater
            bool best1 = iou1 > iou0;
            float max_iou = fmaxf(iou0, iou1);

            float4 bp = best1 ? pb1 : pb0;   // per-component cndmask, no scratch
            float4 bt = best1 ? tb1 : tb0;
            float dx = bp.x - bt.x, dy = bp.y - bt.y, dz = bp.z - bt.z, dw = bp.w - bt.w;
            coord = dx * dx + dy * dy + dz * dz + dw * dw;

            float pr_best = best1 ? pr.y : pr.x;
            float lr_best = best1 ? lr.y : lr.x;
            float dpo = pr_best - max_iou;
            float dio = max_iou - lr_best;
            pobj = dpo * dpo;
            iouL = dio * dio;
        }
    }

    // ---- wave (64-lane) reduction ----
    #pragma unroll
    for (int off = 32; off > 0; off >>= 1) {
        coord += __shfl_down(coord, off);
        cls   += __shfl_down(cls,   off);
        pobj  += __shfl_down(pobj,  off);
        nobj  += __shfl_down(nobj,  off);
        iouL  += __shfl_down(iouL,  off);
    }

    // ---- block reduction (4 waves) ----
    __shared__ float part[4][5];
    int wave = threadIdx.x >> 6;
    int lane = threadIdx.x & 63;
    if (lane == 0) {
        part[wave][0] = coord;
        part[wave][1] = cls;
        part[wave][2] = pobj;
        part[wave][3] = nobj;
        part[wave][4] = iouL;
    }
    __syncthreads();
    if (threadIdx.x == 0) {
        float s0 = part[0][0] + part[1][0] + part[2][0] + part[3][0];
        float s1 = part[0][1] + part[1][1] + part[2][1] + part[3][1];
        float s2 = part[0][2] + part[1][2] + part[2][2] + part[3][2];
        float s3 = part[0][3] + part[1][3] + part[2][3] + part[3][3];
        float s4 = part[0][4] + part[1][4] + part[2][4] + part[3][4];
        atomicAdd(&out[0], L_COORD * INV_BS * s0);  // coord_loss * 5
        atomicAdd(&out[1], INV_BS * s1);            // cls_loss
        atomicAdd(&out[2], INV_BS * s2);            // pobj_loss
        atomicAdd(&out[3], L_NOOBJ * INV_BS * s3);  // nobj_loss * 0.5
        atomicAdd(&out[4], INV_BS * s4);            // iou_loss
    }
}

extern "C" void kernel_launch(void* const* d_in, const int* in_sizes, int n_in,
                              void* d_out, int out_size, void* d_ws, size_t ws_size,
                              hipStream_t stream) {
    const float* pred_cls   = (const float*)d_in[0];
    const float* pred_resp  = (const float*)d_in[1];
    const float* pred_bb    = (const float*)d_in[2];
    const float* label_cls  = (const float*)d_in[3];
    const float* label_resp = (const float*)d_in[4];
    const float* label_bb   = (const float*)d_in[5];
    float* out = (float*)d_out;

    // d_out is poisoned to 0xAA before every launch — zero it (memset node is
    // graph-capturable).
    hipMemsetAsync(out, 0, 5 * sizeof(float), stream);

    int blocks = (NCELL + 255) / 256;  // 3136 blocks, one cell per thread
    yolo_loss_kernel<<<blocks, 256, 0, stream>>>(
        pred_cls, pred_resp, pred_bb, label_cls, label_resp, label_bb, out);
}

// Round 4
// 200.122 us; speedup vs baseline: 1.7602x; 1.7602x over previous
//
#include <hip/hip_runtime.h>

// YOLOv1 loss on MI355X — round 2 kernel (resubmit x2; R2/R3 benches failed on
// GPU acquisition, no counter evidence since R1).
// R1 post-mortem: 216us at 4.8% HBM / 2% VALU => serialization, not BW.
// Suspects: 15,680 same-line atomicAdds (3136 blocks x 5 to one 32B segment,
// cross-XCD bounce) + zero per-thread ILP.
// Fix: per-block partials to d_ws + 1-block finish kernel (no contended
// atomics, no memset node); 4 cells/thread fully unrolled for ILP.

constexpr int NCELL  = 4096 * 14 * 14;   // 802816
constexpr int TPB    = 256;
constexpr int BLOCKS = 784;              // 784*256*4 == NCELL exactly
constexpr int ITERS  = 4;
constexpr int STRIDE = BLOCKS * TPB;     // 200704

constexpr float INV_BS  = 1.0f / 4096.0f;
constexpr float L_COORD = 5.0f;
constexpr float L_NOOBJ = 0.5f;

__device__ __forceinline__ float iou_corners(float4 t, float4 p) {
    float thx = 0.5f * t.z * t.z;
    float thy = 0.5f * t.w * t.w;
    float t_l = t.x - thx, t_t = t.y - thy;
    float t_r = t.x + thx, t_b = t.y + thy;
    float phx = 0.5f * p.z * p.z;
    float phy = 0.5f * p.w * p.w;
    float p_l = p.x - phx, p_t = p.y - phy;
    float p_r = p.x + phx, p_b = p.y + phy;
    float ltx = fmaxf(t_l, p_l), lty = fmaxf(t_t, p_t);
    float rbx = fminf(t_r, p_r), rby = fminf(t_b, p_b);
    float wx = fmaxf(rbx - ltx, 0.0f), wy = fmaxf(rby - lty, 0.0f);
    float inter = wx * wy;
    float a1 = (t_r - t_l) * (t_b - t_t);
    float a2 = (p_r - p_l) * (p_b - p_t);
    return inter / (a1 + a2 - inter);
}

__global__ __launch_bounds__(TPB) void yolo_loss_main(
    const float* __restrict__ pred_cls,    // [NCELL][20]
    const float* __restrict__ pred_resp,   // [NCELL][2]
    const float* __restrict__ pred_bb,     // [NCELL][8]
    const float* __restrict__ label_cls,   // [NCELL][20]
    const float* __restrict__ label_resp,  // [NCELL][2]
    const float* __restrict__ label_bb,    // [NCELL][8]
    float* __restrict__ ws)                // [BLOCKS][8] partials
{
    const int tid0 = blockIdx.x * TPB + threadIdx.x;

    float coord = 0.0f, cls = 0.0f, pobj = 0.0f, nobj = 0.0f, iouL = 0.0f;

    // Hoist all response loads: 8 independent float2 loads in flight.
    float2 lr[ITERS], pr[ITERS];
    #pragma unroll
    for (int it = 0; it < ITERS; ++it) {
        int cell = tid0 + it * STRIDE;
        lr[it] = *reinterpret_cast<const float2*>(label_resp + (size_t)cell * 2);
        pr[it] = *reinterpret_cast<const float2*>(pred_resp  + (size_t)cell * 2);
    }

    #pragma unroll
    for (int it = 0; it < ITERS; ++it) {
        int cell = tid0 + it * STRIDE;
        bool obj = lr[it].x > 0.0f;

        if (!obj) {
            float d0 = pr[it].x - lr[it].x, d1 = pr[it].y - lr[it].y;
            nobj += d0 * d0 + d1 * d1;
        } else {
            const float4* pc = reinterpret_cast<const float4*>(pred_cls  + (size_t)cell * 20);
            const float4* lc = reinterpret_cast<const float4*>(label_cls + (size_t)cell * 20);
            #pragma unroll
            for (int k = 0; k < 5; ++k) {
                float4 a = pc[k], b = lc[k];
                float dx = a.x - b.x, dy = a.y - b.y, dz = a.z - b.z, dw = a.w - b.w;
                cls += dx * dx + dy * dy + dz * dz + dw * dw;
            }

            const float4* pbp = reinterpret_cast<const float4*>(pred_bb  + (size_t)cell * 8);
            const float4* tbp = reinterpret_cast<const float4*>(label_bb + (size_t)cell * 8);
            float4 pb0 = pbp[0], pb1 = pbp[1];
            float4 tb0 = tbp[0], tb1 = tbp[1];

            float iou0 = iou_corners(tb0, pb0);
            float iou1 = iou_corners(tb1, pb1);

            bool best1 = iou1 > iou0;            // argmax: first max wins
            float max_iou = fmaxf(iou0, iou1);

            float4 bp = best1 ? pb1 : pb0;
            float4 bt = best1 ? tb1 : tb0;
            float dx = bp.x - bt.x, dy = bp.y - bt.y, dz = bp.z - bt.z, dw = bp.w - bt.w;
            coord += dx * dx + dy * dy + dz * dz + dw * dw;

            float pr_best = best1 ? pr[it].y : pr[it].x;
            float lr_best = best1 ? lr[it].y : lr[it].x;
            float dpo = pr_best - max_iou;
            float dio = max_iou - lr_best;
            pobj += dpo * dpo;
            iouL += dio * dio;
        }
    }

    // ---- wave (64-lane) reduction ----
    #pragma unroll
    for (int off = 32; off > 0; off >>= 1) {
        coord += __shfl_down(coord, off);
        cls   += __shfl_down(cls,   off);
        pobj  += __shfl_down(pobj,  off);
        nobj  += __shfl_down(nobj,  off);
        iouL  += __shfl_down(iouL,  off);
    }

    // ---- block reduction (4 waves) ----
    __shared__ float part[4][5];
    int wave = threadIdx.x >> 6;
    int lane = threadIdx.x & 63;
    if (lane == 0) {
        part[wave][0] = coord;
        part[wave][1] = cls;
        part[wave][2] = pobj;
        part[wave][3] = nobj;
        part[wave][4] = iouL;
    }
    __syncthreads();
    if (threadIdx.x == 0) {
        float* w = ws + (size_t)blockIdx.x * 8;
        w[0] = part[0][0] + part[1][0] + part[2][0] + part[3][0];
        w[1] = part[0][1] + part[1][1] + part[2][1] + part[3][1];
        w[2] = part[0][2] + part[1][2] + part[2][2] + part[3][2];
        w[3] = part[0][3] + part[1][3] + part[2][3] + part[3][3];
        w[4] = part[0][4] + part[1][4] + part[2][4] + part[3][4];
    }
}

__global__ __launch_bounds__(TPB) void yolo_loss_finish(
    const float* __restrict__ ws,   // [BLOCKS][8]
    float* __restrict__ out)        // [5]
{
    float s0 = 0.0f, s1 = 0.0f, s2 = 0.0f, s3 = 0.0f, s4 = 0.0f;
    for (int b = threadIdx.x; b < BLOCKS; b += TPB) {
        const float* w = ws + (size_t)b * 8;
        s0 += w[0]; s1 += w[1]; s2 += w[2]; s3 += w[3]; s4 += w[4];
    }
    #pragma unroll
    for (int off = 32; off > 0; off >>= 1) {
        s0 += __shfl_down(s0, off);
        s1 += __shfl_down(s1, off);
        s2 += __shfl_down(s2, off);
        s3 += __shfl_down(s3, off);
        s4 += __shfl_down(s4, off);
    }
    __shared__ float part[4][5];
    int wave = threadIdx.x >> 6;
    int lane = threadIdx.x & 63;
    if (lane == 0) {
        part[wave][0] = s0; part[wave][1] = s1; part[wave][2] = s2;
        part[wave][3] = s3; part[wave][4] = s4;
    }
    __syncthreads();
    if (threadIdx.x == 0) {
        float t0 = part[0][0] + part[1][0] + part[2][0] + part[3][0];
        float t1 = part[0][1] + part[1][1] + part[2][1] + part[3][1];
        float t2 = part[0][2] + part[1][2] + part[2][2] + part[3][2];
        float t3 = part[0][3] + part[1][3] + part[2][3] + part[3][3];
        float t4 = part[0][4] + part[1][4] + part[2][4] + part[3][4];
        out[0] = L_COORD * INV_BS * t0;
        out[1] = INV_BS * t1;
        out[2] = INV_BS * t2;
        out[3] = L_NOOBJ * INV_BS * t3;
        out[4] = INV_BS * t4;
    }
}

extern "C" void kernel_launch(void* const* d_in, const int* in_sizes, int n_in,
                              void* d_out, int out_size, void* d_ws, size_t ws_size,
                              hipStream_t stream) {
    const float* pred_cls   = (const float*)d_in[0];
    const float* pred_resp  = (const float*)d_in[1];
    const float* pred_bb    = (const float*)d_in[2];
    const float* label_cls  = (const float*)d_in[3];
    const float* label_resp = (const float*)d_in[4];
    const float* label_bb   = (const float*)d_in[5];
    float* ws  = (float*)d_ws;          // BLOCKS*8 floats = 25 KB
    float* out = (float*)d_out;

    yolo_loss_main<<<BLOCKS, TPB, 0, stream>>>(
        pred_cls, pred_resp, pred_bb, label_cls, label_resp, label_bb, ws);
    yolo_loss_finish<<<1, TPB, 0, stream>>>(ws, out);
}